// Round 5
// baseline (52.937 us; speedup 1.0000x reference)
//
#include <hip/hip_runtime.h>
#include <math.h>

// Problem constants (fixed by the reference setup_inputs)
#define B_   8
#define T_   16
#define HW_  262144                 // 512*512
#define N_   (B_*T_*HW_)            // 33,554,432
#define CHUNKS_PER_FRAME 16
#define NBLOCKS (B_*T_*CHUNKS_PER_FRAME)   // 2048
#define CHUNK_ELEMS (HW_/CHUNKS_PER_FRAME) // 16384
#define THREADS 256

#define BOUND_  100.0f
#define ALPHA_  0.1f
#define SMOOTH_ 1e-5f

typedef float f32x4 __attribute__((ext_vector_type(4)));

__device__ __forceinline__ float wave_reduce(float v) {
    #pragma unroll
    for (int off = 32; off >= 1; off >>= 1)
        v += __shfl_down(v, off, 64);
    return v;
}

struct Acc { float bce, pt, p, t, x; };

__device__ __forceinline__ void accum4(const f32x4 xv, const f32x4 tv, Acc& a) {
    #pragma unroll
    for (int j = 0; j < 4; ++j) {
        float xx = xv[j], tt = tv[j];
        float ax = fabsf(xx);
        float e  = __expf(-ax);                    // shared by bce + sigmoid
        // bce: max(x,0) - x*t + log1p(exp(-|x|)); e in (0,1] so log is safe
        a.bce += fmaxf(xx, 0.f) - xx * tt + __logf(1.f + e);
        float inv = __fdividef(1.f, 1.f + e);
        float sig = (xx >= 0.f) ? inv : e * inv;   // sigmoid via same e
        a.pt += sig * tt;
        a.p  += sig;
        a.t  += tt;
        a.x  += xx;
    }
}

// Pass 1: streaming partials, one contiguous 16K-element chunk per block.
// x loaded normally (134 MB -> LLC-resident across replays); target loaded
// non-temporally (no LLC allocate) so it streams from HBM without evicting x.
// Manual x2 unroll: 4 loads (4 KB/wave) in flight before any use, for MLP.
// Partials in ws: [5][NBLOCKS] = {bce, pt, p, t, x}.
__global__ void __launch_bounds__(THREADS)
partials_kernel(const float* __restrict__ x, const float* __restrict__ tg,
                float* __restrict__ ws) {
    const int bid = blockIdx.x;
    const int tid = threadIdx.x;
    const size_t base = (size_t)bid * CHUNK_ELEMS;
    const f32x4* __restrict__ x4 = (const f32x4*)(x + base);
    const f32x4* __restrict__ t4 = (const f32x4*)(tg + base);

    Acc a = {0.f, 0.f, 0.f, 0.f, 0.f};

    const int n4 = CHUNK_ELEMS / 4;  // 4096 float4 per block; 8 iters/thread
    for (int i = tid; i < n4; i += 2 * THREADS) {
        f32x4 xa = x4[i];
        f32x4 xb = x4[i + THREADS];
        f32x4 ta = __builtin_nontemporal_load(&t4[i]);
        f32x4 tb = __builtin_nontemporal_load(&t4[i + THREADS]);
        accum4(xa, ta, a);
        accum4(xb, tb, a);
    }

    // block reduce (4 waves)
    __shared__ float red[4][5];
    float v[5] = {a.bce, a.pt, a.p, a.t, a.x};
    const int lane = tid & 63, wv = tid >> 6;
    #pragma unroll
    for (int q = 0; q < 5; ++q) {
        float r = wave_reduce(v[q]);
        if (lane == 0) red[wv][q] = r;
    }
    __syncthreads();
    if (tid == 0) {
        #pragma unroll
        for (int q = 0; q < 5; ++q)
            ws[q * NBLOCKS + bid] = red[0][q] + red[1][q] + red[2][q] + red[3][q];
    }
}

// Pass 2: single 256-thread block, fixed-order deterministic reductions.
__global__ void __launch_bounds__(256)
finalize_kernel(const float* __restrict__ ws, float* __restrict__ out) {
    __shared__ float frame_s[B_ * T_];   // 128 per-frame x sums
    __shared__ float batch_q[3][B_];     // pt, p, t per batch
    __shared__ float sred[4];
    __shared__ float ssl_sh;

    const int tid = threadIdx.x;
    const int lane = tid & 63, wv = tid >> 6;

    // phase 1: frame sums from x-partials (threads 0..127)
    if (tid < B_ * T_) {
        const float* wx = ws + 4 * NBLOCKS;
        float s = 0.f;
        #pragma unroll
        for (int j = 0; j < CHUNKS_PER_FRAME; ++j)
            s += wx[tid * CHUNKS_PER_FRAME + j];
        frame_s[tid] = s;
    }
    __syncthreads();

    // phase 2a: per-batch pt/p/t sums — 24 segments x 256 values, 8 threads each
    if (tid < 192) {
        int seg = tid >> 3;          // 0..23
        int q = seg >> 3;            // 0..2  -> ws segments 1..3
        int b = seg & 7;             // 0..7
        const float* wq = ws + (q + 1) * NBLOCKS + b * (NBLOCKS / B_);
        float s = 0.f;
        #pragma unroll
        for (int k = 0; k < 32; ++k)
            s += wq[(tid & 7) * 32 + k];
        s += __shfl_down(s, 4, 64);   // groups of 8 are wave-aligned
        s += __shfl_down(s, 2, 64);
        s += __shfl_down(s, 1, 64);
        if ((tid & 7) == 0) batch_q[q][b] = s;
    }
    // phase 2b: ssl over 120 frame diffs (threads 192..255 = wave 3, 2 diffs each)
    if (tid >= 192) {
        int k = tid - 192;
        float sslp = 0.f;
        #pragma unroll
        for (int u = 0; u < 2; ++u) {
            int kk = k + 64 * u;
            if (kk < B_ * (T_ - 1)) {
                int b = kk / (T_ - 1), j = kk % (T_ - 1);
                int f = b * T_ + j;
                float d = fabsf(frame_s[f + 1] - frame_s[f]);
                float r = fmaxf(d - BOUND_, 0.f);
                sslp += r * r;
            }
        }
        float r = wave_reduce(sslp);
        if (lane == 0) ssl_sh = r;
    }
    __syncthreads();

    // phase 3: global bce sum — 2048 partials, 8 per thread
    {
        float s = 0.f;
        #pragma unroll
        for (int k = 0; k < 8; ++k)
            s += ws[tid * 8 + k];
        float r = wave_reduce(s);
        if (lane == 0) sred[wv] = r;
    }
    __syncthreads();

    if (tid == 0) {
        float bce = (sred[0] + sred[1] + sred[2] + sred[3]) / (float)N_;
        float dice_sum = 0.f;
        #pragma unroll
        for (int b = 0; b < B_; ++b) {
            float inter = batch_q[0][b];
            dice_sum += (2.f * inter + SMOOTH_) /
                        (batch_q[1][b] + batch_q[2][b] + SMOOTH_);
        }
        float dice = 1.f - dice_sum / (float)B_;
        out[0] = 0.5f * bce + dice + ALPHA_ * ssl_sh;
    }
}

extern "C" void kernel_launch(void* const* d_in, const int* in_sizes, int n_in,
                              void* d_out, int out_size, void* d_ws, size_t ws_size,
                              hipStream_t stream) {
    const float* x  = (const float*)d_in[0];
    const float* tg = (const float*)d_in[1];
    float* ws = (float*)d_ws;          // 5*2048*4 = 40 KB partials
    float* out = (float*)d_out;

    partials_kernel<<<NBLOCKS, THREADS, 0, stream>>>(x, tg, ws);
    finalize_kernel<<<1, 256, 0, stream>>>(ws, out);
}

// Round 6
// 49.178 us; speedup vs baseline: 1.0764x; 1.0764x over previous
//
#include <hip/hip_runtime.h>
#include <math.h>

// Problem constants (fixed by the reference setup_inputs)
#define B_   8
#define T_   16
#define HW_  262144                 // 512*512
#define N_   (B_*T_*HW_)            // 33,554,432
#define CHUNKS_PER_FRAME 16
#define NBLOCKS (B_*T_*CHUNKS_PER_FRAME)   // 2048
#define CHUNK_ELEMS (HW_/CHUNKS_PER_FRAME) // 16384
#define THREADS 256

#define BOUND_  100.0f
#define ALPHA_  0.1f
#define SMOOTH_ 1e-5f

#define LOG2E_ 1.4426950408889634f
#define LN2_   0.6931471805599453f

typedef float f32x4 __attribute__((ext_vector_type(4)));

__device__ __forceinline__ float wave_reduce(float v) {
    #pragma unroll
    for (int off = 32; off >= 1; off >>= 1)
        v += __shfl_down(v, off, 64);
    return v;
}

// Pass 1: streaming partials, one contiguous 16K-element chunk per block.
// x loaded normally (134 MB -> LLC-resident across replays); target loaded
// non-temporally (no LLC allocate) so it streams from HBM without evicting x.
// Math in log2 domain, vectorized f32x4 so the compiler emits v_pk_* pairs:
//   e  = exp2(-|x|*c)            (c = log2 e)
//   ld = log2(1+e)               => log1p(exp(-|x|)) = ld*ln2
//   bce += max(x,0) - x*t + ld*ln2
//   sig = exp2(min(x,0)*c - ld)  (= sigmoid(x), branchless, no divide)
// Partials in ws: [5][NBLOCKS] = {bce, pt, p, t, x}.
__global__ void __launch_bounds__(THREADS)
partials_kernel(const float* __restrict__ x, const float* __restrict__ tg,
                float* __restrict__ ws) {
    const int bid = blockIdx.x;
    const int tid = threadIdx.x;
    const size_t base = (size_t)bid * CHUNK_ELEMS;
    const f32x4* __restrict__ x4 = (const f32x4*)(x + base);
    const f32x4* __restrict__ t4 = (const f32x4*)(tg + base);

    f32x4 a_bce = {0.f, 0.f, 0.f, 0.f};
    f32x4 a_pt  = {0.f, 0.f, 0.f, 0.f};
    f32x4 a_p   = {0.f, 0.f, 0.f, 0.f};
    f32x4 a_t   = {0.f, 0.f, 0.f, 0.f};
    f32x4 a_x   = {0.f, 0.f, 0.f, 0.f};
    const f32x4 zero4 = {0.f, 0.f, 0.f, 0.f};

    const int n4 = CHUNK_ELEMS / 4;  // 4096 float4 per block, 16 iters/thread
    for (int i = tid; i < n4; i += THREADS) {
        f32x4 xv = x4[i];
        f32x4 tv = __builtin_nontemporal_load(&t4[i]);

        f32x4 mnx  = __builtin_elementwise_min(xv, -xv);   // -|x|
        f32x4 arge = mnx * LOG2E_;
        f32x4 e;
        #pragma unroll
        for (int j = 0; j < 4; ++j) e[j] = __builtin_amdgcn_exp2f(arge[j]);
        f32x4 d = e + 1.0f;
        f32x4 ld;
        #pragma unroll
        for (int j = 0; j < 4; ++j) ld[j] = __builtin_amdgcn_logf(d[j]); // log2
        f32x4 fm = __builtin_elementwise_max(xv, zero4);
        a_bce += fm - xv * tv + ld * LN2_;
        f32x4 mn  = __builtin_elementwise_min(xv, zero4);
        f32x4 arg = mn * LOG2E_ - ld;
        f32x4 sig;
        #pragma unroll
        for (int j = 0; j < 4; ++j) sig[j] = __builtin_amdgcn_exp2f(arg[j]);
        a_pt += sig * tv;
        a_p  += sig;
        a_t  += tv;
        a_x  += xv;
    }

    // horizontal + block reduce (4 waves)
    __shared__ float red[4][5];
    float v[5] = {a_bce[0] + a_bce[1] + a_bce[2] + a_bce[3],
                  a_pt[0]  + a_pt[1]  + a_pt[2]  + a_pt[3],
                  a_p[0]   + a_p[1]   + a_p[2]   + a_p[3],
                  a_t[0]   + a_t[1]   + a_t[2]   + a_t[3],
                  a_x[0]   + a_x[1]   + a_x[2]   + a_x[3]};
    const int lane = tid & 63, wv = tid >> 6;
    #pragma unroll
    for (int q = 0; q < 5; ++q) {
        float r = wave_reduce(v[q]);
        if (lane == 0) red[wv][q] = r;
    }
    __syncthreads();
    if (tid == 0) {
        #pragma unroll
        for (int q = 0; q < 5; ++q)
            ws[q * NBLOCKS + bid] = red[0][q] + red[1][q] + red[2][q] + red[3][q];
    }
}

// Pass 2: single 256-thread block, fixed-order deterministic reductions.
__global__ void __launch_bounds__(256)
finalize_kernel(const float* __restrict__ ws, float* __restrict__ out) {
    __shared__ float frame_s[B_ * T_];   // 128 per-frame x sums
    __shared__ float batch_q[3][B_];     // pt, p, t per batch
    __shared__ float sred[4];
    __shared__ float ssl_sh;

    const int tid = threadIdx.x;
    const int lane = tid & 63, wv = tid >> 6;

    // phase 1: frame sums from x-partials (threads 0..127)
    if (tid < B_ * T_) {
        const float* wx = ws + 4 * NBLOCKS;
        float s = 0.f;
        #pragma unroll
        for (int j = 0; j < CHUNKS_PER_FRAME; ++j)
            s += wx[tid * CHUNKS_PER_FRAME + j];
        frame_s[tid] = s;
    }
    __syncthreads();

    // phase 2a: per-batch pt/p/t sums — 24 segments x 256 values, 8 threads each
    if (tid < 192) {
        int seg = tid >> 3;          // 0..23
        int q = seg >> 3;            // 0..2  -> ws segments 1..3
        int b = seg & 7;             // 0..7
        const float* wq = ws + (q + 1) * NBLOCKS + b * (NBLOCKS / B_);
        float s = 0.f;
        #pragma unroll
        for (int k = 0; k < 32; ++k)
            s += wq[(tid & 7) * 32 + k];
        s += __shfl_down(s, 4, 64);   // groups of 8 are wave-aligned
        s += __shfl_down(s, 2, 64);
        s += __shfl_down(s, 1, 64);
        if ((tid & 7) == 0) batch_q[q][b] = s;
    }
    // phase 2b: ssl over 120 frame diffs (threads 192..255 = wave 3, 2 diffs each)
    if (tid >= 192) {
        int k = tid - 192;
        float sslp = 0.f;
        #pragma unroll
        for (int u = 0; u < 2; ++u) {
            int kk = k + 64 * u;
            if (kk < B_ * (T_ - 1)) {
                int b = kk / (T_ - 1), j = kk % (T_ - 1);
                int f = b * T_ + j;
                float d = fabsf(frame_s[f + 1] - frame_s[f]);
                float r = fmaxf(d - BOUND_, 0.f);
                sslp += r * r;
            }
        }
        float r = wave_reduce(sslp);
        if (lane == 0) ssl_sh = r;
    }
    __syncthreads();

    // phase 3: global bce sum — 2048 partials, 8 per thread
    {
        float s = 0.f;
        #pragma unroll
        for (int k = 0; k < 8; ++k)
            s += ws[tid * 8 + k];
        float r = wave_reduce(s);
        if (lane == 0) sred[wv] = r;
    }
    __syncthreads();

    if (tid == 0) {
        float bce = (sred[0] + sred[1] + sred[2] + sred[3]) / (float)N_;
        float dice_sum = 0.f;
        #pragma unroll
        for (int b = 0; b < B_; ++b) {
            float inter = batch_q[0][b];
            dice_sum += (2.f * inter + SMOOTH_) /
                        (batch_q[1][b] + batch_q[2][b] + SMOOTH_);
        }
        float dice = 1.f - dice_sum / (float)B_;
        out[0] = 0.5f * bce + dice + ALPHA_ * ssl_sh;
    }
}

extern "C" void kernel_launch(void* const* d_in, const int* in_sizes, int n_in,
                              void* d_out, int out_size, void* d_ws, size_t ws_size,
                              hipStream_t stream) {
    const float* x  = (const float*)d_in[0];
    const float* tg = (const float*)d_in[1];
    float* ws = (float*)d_ws;          // 5*2048*4 = 40 KB partials
    float* out = (float*)d_out;

    partials_kernel<<<NBLOCKS, THREADS, 0, stream>>>(x, tg, ws);
    finalize_kernel<<<1, 256, 0, stream>>>(ws, out);
}

// Round 7
// 48.522 us; speedup vs baseline: 1.0910x; 1.0135x over previous
//
#include <hip/hip_runtime.h>
#include <math.h>

// Problem constants (fixed by the reference setup_inputs)
#define B_   8
#define T_   16
#define HW_  262144                 // 512*512
#define N_   (B_*T_*HW_)            // 33,554,432
#define CHUNKS_PER_FRAME 16
#define NBLOCKS (B_*T_*CHUNKS_PER_FRAME)   // 2048
#define CHUNK_ELEMS (HW_/CHUNKS_PER_FRAME) // 16384
#define THREADS 256

#define BOUND_  100.0f
#define ALPHA_  0.1f
#define SMOOTH_ 1e-5f

#define LOG2E_ 1.4426950408889634f
#define LN2_   0.6931471805599453f

typedef float f32x4 __attribute__((ext_vector_type(4)));

__device__ __forceinline__ float wave_reduce(float v) {
    #pragma unroll
    for (int off = 32; off >= 1; off >>= 1)
        v += __shfl_down(v, off, 64);
    return v;
}

struct Acc5 { f32x4 bce, pt, p, t, x; };

// log2-domain body (validated r6):
//   e  = exp2(-|x|*c); ld = log2(1+e)       (c = log2 e)
//   bce += max(x,0) - x*t + ld*ln2
//   sig  = exp2(min(x,0)*c - ld)            (branchless sigmoid, no divide)
__device__ __forceinline__ void accum4(const f32x4 xv, const f32x4 tv, Acc5& a) {
    const f32x4 zero4 = {0.f, 0.f, 0.f, 0.f};
    f32x4 mnx  = __builtin_elementwise_min(xv, -xv);   // -|x|
    f32x4 arge = mnx * LOG2E_;
    f32x4 e;
    #pragma unroll
    for (int j = 0; j < 4; ++j) e[j] = __builtin_amdgcn_exp2f(arge[j]);
    f32x4 d = e + 1.0f;
    f32x4 ld;
    #pragma unroll
    for (int j = 0; j < 4; ++j) ld[j] = __builtin_amdgcn_logf(d[j]); // log2
    f32x4 fm = __builtin_elementwise_max(xv, zero4);
    a.bce += fm - xv * tv + ld * LN2_;
    f32x4 mn  = __builtin_elementwise_min(xv, zero4);
    f32x4 arg = mn * LOG2E_ - ld;
    f32x4 sig;
    #pragma unroll
    for (int j = 0; j < 4; ++j) sig[j] = __builtin_amdgcn_exp2f(arg[j]);
    a.pt += sig * tv;
    a.p  += sig;
    a.t  += tv;
    a.x  += xv;
}

// Pass 1: streaming partials, one contiguous 16K-element chunk per block.
// x loaded normally (134 MB -> LLC-resident); target loaded non-temporally
// (no LLC allocate, streams from HBM). Manual 4-pair load batch: 8 dwordx4
// loads (128 B/lane) issued before any use — memory-level parallelism.
// Partials in ws: [5][NBLOCKS] = {bce, pt, p, t, x}.
__global__ void __launch_bounds__(THREADS)
partials_kernel(const float* __restrict__ x, const float* __restrict__ tg,
                float* __restrict__ ws) {
    const int bid = blockIdx.x;
    const int tid = threadIdx.x;
    const size_t base = (size_t)bid * CHUNK_ELEMS;
    const f32x4* __restrict__ x4 = (const f32x4*)(x + base);
    const f32x4* __restrict__ t4 = (const f32x4*)(tg + base);

    Acc5 a;
    a.bce = a.pt = a.p = a.t = a.x = (f32x4){0.f, 0.f, 0.f, 0.f};

    const int n4 = CHUNK_ELEMS / 4;  // 4096 float4 per block; 4 outer iters
    for (int i = tid; i < n4; i += 4 * THREADS) {
        f32x4 xa = x4[i];
        f32x4 xb = x4[i + THREADS];
        f32x4 xc = x4[i + 2 * THREADS];
        f32x4 xd = x4[i + 3 * THREADS];
        f32x4 ta = __builtin_nontemporal_load(&t4[i]);
        f32x4 tb = __builtin_nontemporal_load(&t4[i + THREADS]);
        f32x4 tc = __builtin_nontemporal_load(&t4[i + 2 * THREADS]);
        f32x4 td = __builtin_nontemporal_load(&t4[i + 3 * THREADS]);
        accum4(xa, ta, a);
        accum4(xb, tb, a);
        accum4(xc, tc, a);
        accum4(xd, td, a);
    }

    // horizontal + block reduce (4 waves)
    __shared__ float red[4][5];
    float v[5] = {a.bce[0] + a.bce[1] + a.bce[2] + a.bce[3],
                  a.pt[0]  + a.pt[1]  + a.pt[2]  + a.pt[3],
                  a.p[0]   + a.p[1]   + a.p[2]   + a.p[3],
                  a.t[0]   + a.t[1]   + a.t[2]   + a.t[3],
                  a.x[0]   + a.x[1]   + a.x[2]   + a.x[3]};
    const int lane = tid & 63, wv = tid >> 6;
    #pragma unroll
    for (int q = 0; q < 5; ++q) {
        float r = wave_reduce(v[q]);
        if (lane == 0) red[wv][q] = r;
    }
    __syncthreads();
    if (tid == 0) {
        #pragma unroll
        for (int q = 0; q < 5; ++q)
            ws[q * NBLOCKS + bid] = red[0][q] + red[1][q] + red[2][q] + red[3][q];
    }
}

// Pass 2: single 256-thread block, fixed-order deterministic reductions.
__global__ void __launch_bounds__(256)
finalize_kernel(const float* __restrict__ ws, float* __restrict__ out) {
    __shared__ float frame_s[B_ * T_];   // 128 per-frame x sums
    __shared__ float batch_q[3][B_];     // pt, p, t per batch
    __shared__ float sred[4];
    __shared__ float ssl_sh;

    const int tid = threadIdx.x;
    const int lane = tid & 63, wv = tid >> 6;

    // phase 1: frame sums from x-partials (threads 0..127)
    if (tid < B_ * T_) {
        const float* wx = ws + 4 * NBLOCKS;
        float s = 0.f;
        #pragma unroll
        for (int j = 0; j < CHUNKS_PER_FRAME; ++j)
            s += wx[tid * CHUNKS_PER_FRAME + j];
        frame_s[tid] = s;
    }
    __syncthreads();

    // phase 2a: per-batch pt/p/t sums — 24 segments x 256 values, 8 threads each
    if (tid < 192) {
        int seg = tid >> 3;          // 0..23
        int q = seg >> 3;            // 0..2  -> ws segments 1..3
        int b = seg & 7;             // 0..7
        const float* wq = ws + (q + 1) * NBLOCKS + b * (NBLOCKS / B_);
        float s = 0.f;
        #pragma unroll
        for (int k = 0; k < 32; ++k)
            s += wq[(tid & 7) * 32 + k];
        s += __shfl_down(s, 4, 64);   // groups of 8 are wave-aligned
        s += __shfl_down(s, 2, 64);
        s += __shfl_down(s, 1, 64);
        if ((tid & 7) == 0) batch_q[q][b] = s;
    }
    // phase 2b: ssl over 120 frame diffs (threads 192..255 = wave 3, 2 diffs each)
    if (tid >= 192) {
        int k = tid - 192;
        float sslp = 0.f;
        #pragma unroll
        for (int u = 0; u < 2; ++u) {
            int kk = k + 64 * u;
            if (kk < B_ * (T_ - 1)) {
                int b = kk / (T_ - 1), j = kk % (T_ - 1);
                int f = b * T_ + j;
                float d = fabsf(frame_s[f + 1] - frame_s[f]);
                float r = fmaxf(d - BOUND_, 0.f);
                sslp += r * r;
            }
        }
        float r = wave_reduce(sslp);
        if (lane == 0) ssl_sh = r;
    }
    __syncthreads();

    // phase 3: global bce sum — 2048 partials, 8 per thread
    {
        float s = 0.f;
        #pragma unroll
        for (int k = 0; k < 8; ++k)
            s += ws[tid * 8 + k];
        float r = wave_reduce(s);
        if (lane == 0) sred[wv] = r;
    }
    __syncthreads();

    if (tid == 0) {
        float bce = (sred[0] + sred[1] + sred[2] + sred[3]) / (float)N_;
        float dice_sum = 0.f;
        #pragma unroll
        for (int b = 0; b < B_; ++b) {
            float inter = batch_q[0][b];
            dice_sum += (2.f * inter + SMOOTH_) /
                        (batch_q[1][b] + batch_q[2][b] + SMOOTH_);
        }
        float dice = 1.f - dice_sum / (float)B_;
        out[0] = 0.5f * bce + dice + ALPHA_ * ssl_sh;
    }
}

extern "C" void kernel_launch(void* const* d_in, const int* in_sizes, int n_in,
                              void* d_out, int out_size, void* d_ws, size_t ws_size,
                              hipStream_t stream) {
    const float* x  = (const float*)d_in[0];
    const float* tg = (const float*)d_in[1];
    float* ws = (float*)d_ws;          // 5*2048*4 = 40 KB partials
    float* out = (float*)d_out;

    partials_kernel<<<NBLOCKS, THREADS, 0, stream>>>(x, tg, ws);
    finalize_kernel<<<1, 256, 0, stream>>>(ws, out);
}

// Round 8
// 48.174 us; speedup vs baseline: 1.0989x; 1.0072x over previous
//
#include <hip/hip_runtime.h>
#include <math.h>

// Problem constants (fixed by the reference setup_inputs)
#define B_   8
#define T_   16
#define HW_  262144                 // 512*512
#define N_   (B_*T_*HW_)            // 33,554,432
#define CHUNKS_PER_FRAME 16
#define NBLOCKS (B_*T_*CHUNKS_PER_FRAME)   // 2048
#define CHUNK_ELEMS (HW_/CHUNKS_PER_FRAME) // 16384
#define THREADS 256

#define BOUND_  100.0f
#define ALPHA_  0.1f
#define SMOOTH_ 1e-5f

#define LOG2E_ 1.4426950408889634f
#define LN2_   0.6931471805599453f

typedef float f32x4 __attribute__((ext_vector_type(4)));

__device__ __forceinline__ float wave_reduce(float v) {
    #pragma unroll
    for (int off = 32; off >= 1; off >>= 1)
        v += __shfl_down(v, off, 64);
    return v;
}

struct Acc5 { f32x4 bce, pt, p, t, x; };

// log2-domain body (validated r6):
//   e  = exp2(-|x|*c); ld = log2(1+e)       (c = log2 e)
//   bce += max(x,0) - x*t + ld*ln2
//   sig  = exp2(min(x,0)*c - ld)            (branchless sigmoid, no divide)
__device__ __forceinline__ void accum4(const f32x4 xv, const f32x4 tv, Acc5& a) {
    const f32x4 zero4 = {0.f, 0.f, 0.f, 0.f};
    f32x4 mnx  = __builtin_elementwise_min(xv, -xv);   // -|x|
    f32x4 arge = mnx * LOG2E_;
    f32x4 e;
    #pragma unroll
    for (int j = 0; j < 4; ++j) e[j] = __builtin_amdgcn_exp2f(arge[j]);
    f32x4 d = e + 1.0f;
    f32x4 ld;
    #pragma unroll
    for (int j = 0; j < 4; ++j) ld[j] = __builtin_amdgcn_logf(d[j]); // log2
    f32x4 fm = __builtin_elementwise_max(xv, zero4);
    a.bce += fm - xv * tv + ld * LN2_;
    f32x4 mn  = __builtin_elementwise_min(xv, zero4);
    f32x4 arg = mn * LOG2E_ - ld;
    f32x4 sig;
    #pragma unroll
    for (int j = 0; j < 4; ++j) sig[j] = __builtin_amdgcn_exp2f(arg[j]);
    a.pt += sig * tv;
    a.p  += sig;
    a.t  += tv;
    a.x  += xv;
}

// Pass 1 (UNCHANGED from r7 — at the fabric read ceiling):
// x loaded normally (134 MB -> LLC-resident); target loaded non-temporally
// (no LLC allocate, streams from HBM). 4-pair load batch for MLP.
// Partials in ws: [5][NBLOCKS] = {bce, pt, p, t, x}.
__global__ void __launch_bounds__(THREADS)
partials_kernel(const float* __restrict__ x, const float* __restrict__ tg,
                float* __restrict__ ws) {
    const int bid = blockIdx.x;
    const int tid = threadIdx.x;
    const size_t base = (size_t)bid * CHUNK_ELEMS;
    const f32x4* __restrict__ x4 = (const f32x4*)(x + base);
    const f32x4* __restrict__ t4 = (const f32x4*)(tg + base);

    Acc5 a;
    a.bce = a.pt = a.p = a.t = a.x = (f32x4){0.f, 0.f, 0.f, 0.f};

    const int n4 = CHUNK_ELEMS / 4;  // 4096 float4 per block; 4 outer iters
    for (int i = tid; i < n4; i += 4 * THREADS) {
        f32x4 xa = x4[i];
        f32x4 xb = x4[i + THREADS];
        f32x4 xc = x4[i + 2 * THREADS];
        f32x4 xd = x4[i + 3 * THREADS];
        f32x4 ta = __builtin_nontemporal_load(&t4[i]);
        f32x4 tb = __builtin_nontemporal_load(&t4[i + THREADS]);
        f32x4 tc = __builtin_nontemporal_load(&t4[i + 2 * THREADS]);
        f32x4 td = __builtin_nontemporal_load(&t4[i + 3 * THREADS]);
        accum4(xa, ta, a);
        accum4(xb, tb, a);
        accum4(xc, tc, a);
        accum4(xd, td, a);
    }

    // horizontal + block reduce (4 waves)
    __shared__ float red[4][5];
    float v[5] = {a.bce[0] + a.bce[1] + a.bce[2] + a.bce[3],
                  a.pt[0]  + a.pt[1]  + a.pt[2]  + a.pt[3],
                  a.p[0]   + a.p[1]   + a.p[2]   + a.p[3],
                  a.t[0]   + a.t[1]   + a.t[2]   + a.t[3],
                  a.x[0]   + a.x[1]   + a.x[2]   + a.x[3]};
    const int lane = tid & 63, wv = tid >> 6;
    #pragma unroll
    for (int q = 0; q < 5; ++q) {
        float r = wave_reduce(v[q]);
        if (lane == 0) red[wv][q] = r;
    }
    __syncthreads();
    if (tid == 0) {
        #pragma unroll
        for (int q = 0; q < 5; ++q)
            ws[q * NBLOCKS + bid] = red[0][q] + red[1][q] + red[2][q] + red[3][q];
    }
}

// Pass 2: SINGLE WAVE (64 threads) — zero __syncthreads, zero LDS.
// All reductions wave-synchronous via shuffles. Fixed order => deterministic.
__global__ void __launch_bounds__(64)
finalize_kernel(const float* __restrict__ ws, float* __restrict__ out) {
    const int l = threadIdx.x;   // lane 0..63

    // ---- global bce sum: 2048 partials, 32 strided per lane (coalesced) ----
    float s_bce = 0.f;
    #pragma unroll
    for (int k = 0; k < 32; ++k)
        s_bce += ws[l + 64 * k];
    float r_bce = wave_reduce(s_bce);     // valid in lane 0

    // ---- per-batch pt/p/t: lane l -> batch b=l>>3, slice j=l&7 (32 contiguous) ----
    float bsum[3];
    #pragma unroll
    for (int q = 0; q < 3; ++q) {
        const float* wq = ws + (q + 1) * NBLOCKS + (l >> 3) * 256 + (l & 7) * 32;
        float s = 0.f;
        #pragma unroll
        for (int k = 0; k < 32; ++k)
            s += wq[k];
        s += __shfl_down(s, 4, 64);   // 8-lane groups are shuffle-aligned
        s += __shfl_down(s, 2, 64);
        s += __shfl_down(s, 1, 64);
        bsum[q] = s;                  // batch total lives in lanes 0,8,...,56
    }

    // ---- frame sums: 128 frames in two register halves (16 contiguous each) ----
    const float* wx = ws + 4 * NBLOCKS;
    float fs0 = 0.f, fs1 = 0.f;
    #pragma unroll
    for (int k = 0; k < 16; ++k) fs0 += wx[l * 16 + k];          // frames 0..63
    #pragma unroll
    for (int k = 0; k < 16; ++k) fs1 += wx[1024 + l * 16 + k];   // frames 64..127

    // ---- ssl: diffs within each half (batch boundaries at l%16==15 masked) ----
    float n0 = __shfl_down(fs0, 1, 64);
    float n1 = __shfl_down(fs1, 1, 64);
    float sslp = 0.f;
    if ((l & 15) != 15) {
        float d0 = fmaxf(fabsf(n0 - fs0) - BOUND_, 0.f);
        float d1 = fmaxf(fabsf(n1 - fs1) - BOUND_, 0.f);
        sslp = d0 * d0 + d1 * d1;
    }
    float r_ssl = wave_reduce(sslp);      // valid in lane 0

    // ---- final combine: lane 0 gathers batch sums via uniform shfl ----
    float dice_sum = 0.f;
    #pragma unroll
    for (int b = 0; b < B_; ++b) {
        float inter = __shfl(bsum[0], b * 8, 64);
        float pp    = __shfl(bsum[1], b * 8, 64);
        float tt    = __shfl(bsum[2], b * 8, 64);
        dice_sum += (2.f * inter + SMOOTH_) / (pp + tt + SMOOTH_);
    }
    if (l == 0) {
        float bce  = r_bce / (float)N_;
        float dice = 1.f - dice_sum / (float)B_;
        out[0] = 0.5f * bce + dice + ALPHA_ * r_ssl;
    }
}

extern "C" void kernel_launch(void* const* d_in, const int* in_sizes, int n_in,
                              void* d_out, int out_size, void* d_ws, size_t ws_size,
                              hipStream_t stream) {
    const float* x  = (const float*)d_in[0];
    const float* tg = (const float*)d_in[1];
    float* ws = (float*)d_ws;          // 5*2048*4 = 40 KB partials
    float* out = (float*)d_out;

    partials_kernel<<<NBLOCKS, THREADS, 0, stream>>>(x, tg, ws);
    finalize_kernel<<<1, 64, 0, stream>>>(ws, out);
}